// Round 1
// baseline (868.867 us; speedup 1.0000x reference)
//
#include <hip/hip_runtime.h>
#include <hip/hip_bf16.h>
#include <math.h>

#define BB 4
#define CC 64
#define OO 64
#define HH 96
#define WW 320
#define HWP (HH*WW)   // 30720
#define NPIX (BB*HWP) // 122880

// ---------------------------------------------------------------------------
// K1: global MLP -> g (B,32), then Gsum[b][o][k] = sum_{ci<32} g[b,ci]*fuse_w1[o,ci,k]
// ---------------------------------------------------------------------------
__global__ void k_glob(const float* __restrict__ sb,
                       const float* __restrict__ gw1, const float* __restrict__ gb1,
                       const float* __restrict__ gw2, const float* __restrict__ gb2,
                       const float* __restrict__ fw1,
                       float* __restrict__ gsum) {
    __shared__ float g_s[BB * 32];
    int tid = threadIdx.x;  // 128 threads
    if (tid < 128) {
        int b = tid >> 5, i = tid & 31;
        float b0 = sb[b * 5 + 4] - sb[b * 5 + 2];
        float b1 = sb[b * 5 + 3] - sb[b * 5 + 1];
        float acc = gb2[i];
        for (int j = 0; j < 64; ++j) {
            float h1 = b0 * gw1[j * 2 + 0] + b1 * gw1[j * 2 + 1] + gb1[j];
            h1 = fmaxf(h1, 0.f);
            acc += gw2[i * 64 + j] * h1;
        }
        g_s[b * 32 + i] = acc;
    }
    __syncthreads();
    for (int e = tid; e < BB * 32 * 9; e += blockDim.x) {
        int b = e / 288, r = e % 288, o = r / 9, k = r % 9;
        float s = 0.f;
        for (int ci = 0; ci < 32; ++ci)
            s += g_s[b * 32 + ci] * fw1[o * 576 + ci * 9 + k];
        gsum[e] = s;
    }
}

// ---------------------------------------------------------------------------
// K2: loc path: l = conv1x1(relu(conv3x3(x, loc_w1)+b1), loc_w2)+b2   (B,32,H,W)
// one thread per pixel, 32 accumulators
// ---------------------------------------------------------------------------
__global__ __launch_bounds__(256) void k_loc(const float* __restrict__ x,
                      const float* __restrict__ lw1, const float* __restrict__ lb1,
                      const float* __restrict__ lw2, const float* __restrict__ lb2,
                      float* __restrict__ lout) {
    int p = blockIdx.x * blockDim.x + threadIdx.x;
    if (p >= NPIX) return;
    int b = p / HWP;
    int rem = p % HWP;
    int y = rem / WW;
    int xx = rem % WW;

    float acc[32];
#pragma unroll
    for (int o = 0; o < 32; ++o) acc[o] = lb1[o];

    const float* xb = x + (size_t)b * CC * HWP;
    for (int ci = 0; ci < CC; ++ci) {
        const float* xp = xb + ci * HWP;
        float t[9];
#pragma unroll
        for (int kh = 0; kh < 3; ++kh)
#pragma unroll
            for (int kw = 0; kw < 3; ++kw) {
                int yy = y + kh - 1, xw = xx + kw - 1;
                bool v = (yy >= 0) && (yy < HH) && (xw >= 0) && (xw < WW);
                t[kh * 3 + kw] = v ? xp[yy * WW + xw] : 0.f;
            }
        const float* wp = lw1 + ci * 9;
#pragma unroll
        for (int o = 0; o < 32; ++o) {
            const float* w = wp + o * 576;
            float s = acc[o];
#pragma unroll
            for (int k = 0; k < 9; ++k) s += t[k] * w[k];
            acc[o] = s;
        }
    }
#pragma unroll
    for (int o = 0; o < 32; ++o) acc[o] = fmaxf(acc[o], 0.f);

#pragma unroll
    for (int o2 = 0; o2 < 32; ++o2) {
        float s = lb2[o2];
#pragma unroll
        for (int o = 0; o < 32; ++o) s += lw2[o2 * 32 + o] * acc[o];
        lout[((size_t)b * 32 + o2) * HWP + rem] = s;
    }
}

// ---------------------------------------------------------------------------
// K3: mega kernel: fuse conv (using Gsum for the g-channels) -> f -> offset,
//     mask conv -> sigmoid, then deformable conv -> out (B,64,H,W)
// one thread per pixel, 64 output accumulators
// ---------------------------------------------------------------------------
__global__ __launch_bounds__(256) void k_main(const float* __restrict__ x,
                       const float* __restrict__ l,
                       const float* __restrict__ gsum,
                       const float* __restrict__ fw1, const float* __restrict__ fb1,
                       const float* __restrict__ fw2, const float* __restrict__ fb2,
                       const float* __restrict__ mw, const float* __restrict__ mb,
                       const float* __restrict__ cw, const float* __restrict__ cb,
                       float* __restrict__ out) {
    int p = blockIdx.x * blockDim.x + threadIdx.x;
    if (p >= NPIX) return;
    int b = p / HWP;
    int rem = p % HWP;
    int y = rem / WW;
    int xx = rem % WW;

    // ---- Phase A: f[32] = relu(fuse conv3x3 over [g_offset, l]) ----
    float f[32];
#pragma unroll
    for (int o = 0; o < 32; ++o) f[o] = fb1[o];

    const float* lb_ = l + (size_t)b * 32 * HWP;
#pragma unroll
    for (int kh = 0; kh < 3; ++kh) {
#pragma unroll
        for (int kw = 0; kw < 3; ++kw) {
            int yy = y + kh - 1, xw = xx + kw - 1;
            if (yy < 0 || yy >= HH || xw < 0 || xw >= WW) continue;
            int k = kh * 3 + kw;
            // constant (g) channels: precomputed Gsum, valid taps only
#pragma unroll
            for (int o = 0; o < 32; ++o) f[o] += gsum[(b * 32 + o) * 9 + k];
            int off = yy * WW + xw;
            for (int cl = 0; cl < 32; ++cl) {
                float t = lb_[cl * HWP + off];
                const float* w = fw1 + (32 + cl) * 9 + k;
#pragma unroll
                for (int o = 0; o < 32; ++o) f[o] += t * w[o * 576];
            }
        }
    }
#pragma unroll
    for (int o = 0; o < 32; ++o) f[o] = fmaxf(f[o], 0.f);

    // ---- Phase B: offset (18 = 9 x {dy,dx}) via 1x1 conv fuse_w2 ----
    float dy[9], dx[9];
#pragma unroll
    for (int k = 0; k < 9; ++k) {
        float sy = fb2[2 * k], sx = fb2[2 * k + 1];
#pragma unroll
        for (int o = 0; o < 32; ++o) {
            sy += fw2[(2 * k) * 32 + o] * f[o];
            sx += fw2[(2 * k + 1) * 32 + o] * f[o];
        }
        dy[k] = sy;
        dx[k] = sx;
    }

    // ---- Phase C: mask[9] = sigmoid(conv3x3(x, mask_w)) ----
    float m[9];
#pragma unroll
    for (int k2 = 0; k2 < 9; ++k2) m[k2] = mb[k2];
    const float* xb = x + (size_t)b * CC * HWP;
    for (int ci = 0; ci < CC; ++ci) {
        const float* xp = xb + ci * HWP;
        float t[9];
#pragma unroll
        for (int kh = 0; kh < 3; ++kh)
#pragma unroll
            for (int kw = 0; kw < 3; ++kw) {
                int yy = y + kh - 1, xw = xx + kw - 1;
                bool v = (yy >= 0) && (yy < HH) && (xw >= 0) && (xw < WW);
                t[kh * 3 + kw] = v ? xp[yy * WW + xw] : 0.f;
            }
#pragma unroll
        for (int k2 = 0; k2 < 9; ++k2) {
            const float* w = mw + k2 * 576 + ci * 9;
            float s = m[k2];
#pragma unroll
            for (int k = 0; k < 9; ++k) s += t[k] * w[k];
            m[k2] = s;
        }
    }
#pragma unroll
    for (int k = 0; k < 9; ++k) m[k] = 1.f / (1.f + __expf(-m[k]));

    // ---- Phase D: deformable conv ----
    float acc[64];
#pragma unroll
    for (int o = 0; o < 64; ++o) acc[o] = cb[o];

#pragma unroll
    for (int k = 0; k < 9; ++k) {
        int kh = k / 3, kw = k % 3;
        float ys = (float)(y + kh - 1) + dy[k];
        float xs = (float)(xx + kw - 1) + dx[k];
        float y0f = floorf(ys), x0f = floorf(xs);
        int y0 = (int)y0f, x0 = (int)x0f;
        float wy = ys - y0f, wx = xs - x0f;
        float mk = m[k];
        float c00 = (1.f - wy) * (1.f - wx) * mk;
        float c01 = (1.f - wy) * wx * mk;
        float c10 = wy * (1.f - wx) * mk;
        float c11 = wy * wx * mk;
        bool vy0 = (y0 >= 0) && (y0 < HH);
        bool vy1 = (y0 + 1 >= 0) && (y0 + 1 < HH);
        bool vx0 = (x0 >= 0) && (x0 < WW);
        bool vx1 = (x0 + 1 >= 0) && (x0 + 1 < WW);
        c00 = (vy0 && vx0) ? c00 : 0.f;
        c01 = (vy0 && vx1) ? c01 : 0.f;
        c10 = (vy1 && vx0) ? c10 : 0.f;
        c11 = (vy1 && vx1) ? c11 : 0.f;
        int yc0 = min(max(y0, 0), HH - 1), yc1 = min(max(y0 + 1, 0), HH - 1);
        int xc0 = min(max(x0, 0), WW - 1), xc1 = min(max(x0 + 1, 0), WW - 1);
        int i00 = yc0 * WW + xc0, i01 = yc0 * WW + xc1;
        int i10 = yc1 * WW + xc0, i11 = yc1 * WW + xc1;

        for (int ci = 0; ci < CC; ++ci) {
            const float* xp = xb + ci * HWP;
            float v = c00 * xp[i00] + c01 * xp[i01] + c10 * xp[i10] + c11 * xp[i11];
            const float* w = cw + ci * 9 + k;
#pragma unroll
            for (int o = 0; o < 64; ++o) acc[o] += v * w[o * 576];
        }
    }

    float* ob = out + (size_t)b * OO * HWP + rem;
#pragma unroll
    for (int o = 0; o < 64; ++o) ob[(size_t)o * HWP] = acc[o];
}

// ---------------------------------------------------------------------------
extern "C" void kernel_launch(void* const* d_in, const int* in_sizes, int n_in,
                              void* d_out, int out_size, void* d_ws, size_t ws_size,
                              hipStream_t stream) {
    const float* x   = (const float*)d_in[0];
    const float* sb  = (const float*)d_in[1];
    const float* gw1 = (const float*)d_in[2];
    const float* gb1 = (const float*)d_in[3];
    const float* gw2 = (const float*)d_in[4];
    const float* gb2 = (const float*)d_in[5];
    const float* lw1 = (const float*)d_in[6];
    const float* lb1 = (const float*)d_in[7];
    const float* lw2 = (const float*)d_in[8];
    const float* lb2 = (const float*)d_in[9];
    const float* fw1 = (const float*)d_in[10];
    const float* fb1 = (const float*)d_in[11];
    const float* fw2 = (const float*)d_in[12];
    const float* fb2 = (const float*)d_in[13];
    const float* mw  = (const float*)d_in[14];
    const float* mb  = (const float*)d_in[15];
    const float* cw  = (const float*)d_in[16];
    const float* cb  = (const float*)d_in[17];
    float* out = (float*)d_out;

    float* gsum = (float*)d_ws;          // 1152 floats
    float* lbuf = gsum + 1152;           // B*32*H*W floats (~15.7 MB)

    k_glob<<<1, 128, 0, stream>>>(sb, gw1, gb1, gw2, gb2, fw1, gsum);
    k_loc<<<(NPIX + 255) / 256, 256, 0, stream>>>(x, lw1, lb1, lw2, lb2, lbuf);
    k_main<<<(NPIX + 255) / 256, 256, 0, stream>>>(x, lbuf, gsum, fw1, fb1,
                                                   fw2, fb2, mw, mb, cw, cb, out);
}

// Round 2
// 749.599 us; speedup vs baseline: 1.1591x; 1.1591x over previous
//
#include <hip/hip_runtime.h>
#include <hip/hip_bf16.h>
#include <math.h>

#define BB 4
#define CC 64
#define OO 64
#define HH 96
#define WW 320
#define HWP (HH*WW)   // 30720
#define NPIX (BB*HWP) // 122880

// ---------------------------------------------------------------------------
// K1: global MLP -> g (B,32), Gsum[b][o][k] = sum_ci g[b,ci]*fuse_w1[o,ci,k]
// ---------------------------------------------------------------------------
__global__ void k_glob(const float* __restrict__ sb,
                       const float* __restrict__ gw1, const float* __restrict__ gb1,
                       const float* __restrict__ gw2, const float* __restrict__ gb2,
                       const float* __restrict__ fw1,
                       float* __restrict__ gsum) {
    __shared__ float g_s[BB * 32];
    int tid = threadIdx.x;  // 128 threads
    if (tid < 128) {
        int b = tid >> 5, i = tid & 31;
        float b0 = sb[b * 5 + 4] - sb[b * 5 + 2];
        float b1 = sb[b * 5 + 3] - sb[b * 5 + 1];
        float acc = gb2[i];
        for (int j = 0; j < 64; ++j) {
            float h1 = b0 * gw1[j * 2 + 0] + b1 * gw1[j * 2 + 1] + gb1[j];
            h1 = fmaxf(h1, 0.f);
            acc += gw2[i * 64 + j] * h1;
        }
        g_s[b * 32 + i] = acc;
    }
    __syncthreads();
    for (int e = tid; e < BB * 32 * 9; e += blockDim.x) {
        int b = e / 288, r = e % 288, o = r / 9, k = r % 9;
        float s = 0.f;
        for (int ci = 0; ci < 32; ++ci)
            s += g_s[b * 32 + ci] * fw1[o * 576 + ci * 9 + k];
        gsum[e] = s;
    }
}

// ---------------------------------------------------------------------------
// K_wt: transpose conv_w [o][ci][k] -> cwT [k][ci][o] for coalesced staging
// ---------------------------------------------------------------------------
__global__ void k_wt(const float* __restrict__ cw, float* __restrict__ cwT) {
    int e = blockIdx.x * 256 + threadIdx.x;
    if (e >= 9 * 64 * 64) return;
    int k = e >> 12;        // /4096
    int r = e & 4095;
    int ci = r >> 6;
    int o = r & 63;
    cwT[e] = cw[o * 576 + ci * 9 + k];
}

// ---------------------------------------------------------------------------
// K2: fused loc path + mask conv (both read the same x 3x3 neighborhood):
//   l = conv1x1(relu(conv3x3(x,loc_w1)+b1),loc_w2)+b2   (write 32 ch)
//   m = sigmoid(conv3x3(x,mask_w)+mb)                   (write 9 planes [k][p])
// ---------------------------------------------------------------------------
__global__ __launch_bounds__(256) void k_locmask(
        const float* __restrict__ x,
        const float* __restrict__ lw1, const float* __restrict__ lb1,
        const float* __restrict__ lw2, const float* __restrict__ lb2,
        const float* __restrict__ mw, const float* __restrict__ mb,
        float* __restrict__ lout, float* __restrict__ mout) {
    int p = blockIdx.x * blockDim.x + threadIdx.x;
    if (p >= NPIX) return;
    int b = p / HWP;
    int rem = p % HWP;
    int y = rem / WW;
    int xx = rem % WW;

    float la[32];
#pragma unroll
    for (int o = 0; o < 32; ++o) la[o] = lb1[o];
    float ma[9];
#pragma unroll
    for (int j = 0; j < 9; ++j) ma[j] = mb[j];

    const float* xb = x + (size_t)b * CC * HWP;
    for (int ci = 0; ci < CC; ++ci) {
        const float* xp = xb + ci * HWP;
        float t[9];
#pragma unroll
        for (int kh = 0; kh < 3; ++kh)
#pragma unroll
            for (int kw = 0; kw < 3; ++kw) {
                int yy = y + kh - 1, xw = xx + kw - 1;
                bool v = (yy >= 0) && (yy < HH) && (xw >= 0) && (xw < WW);
                t[kh * 3 + kw] = v ? xp[yy * WW + xw] : 0.f;
            }
        const float* wp = lw1 + ci * 9;
#pragma unroll
        for (int o = 0; o < 32; ++o) {
            const float* w = wp + o * 576;
            float s = la[o];
#pragma unroll
            for (int k = 0; k < 9; ++k) s += t[k] * w[k];
            la[o] = s;
        }
        const float* wm = mw + ci * 9;
#pragma unroll
        for (int j = 0; j < 9; ++j) {
            const float* w = wm + j * 576;
            float s = ma[j];
#pragma unroll
            for (int k = 0; k < 9; ++k) s += t[k] * w[k];
            ma[j] = s;
        }
    }
#pragma unroll
    for (int o = 0; o < 32; ++o) la[o] = fmaxf(la[o], 0.f);

#pragma unroll
    for (int o2 = 0; o2 < 32; ++o2) {
        float s = lb2[o2];
#pragma unroll
        for (int o = 0; o < 32; ++o) s += lw2[o2 * 32 + o] * la[o];
        lout[((size_t)b * 32 + o2) * HWP + rem] = s;
    }
#pragma unroll
    for (int j = 0; j < 9; ++j)
        mout[(size_t)j * NPIX + p] = 1.f / (1.f + __expf(-ma[j]));
}

// ---------------------------------------------------------------------------
// K3: fuse conv (Gsum for the g-channels) -> f -> offsets -> sample coords
//     writes ys[k][p], xs[k][p] (absolute sampling coords)
// ---------------------------------------------------------------------------
__global__ __launch_bounds__(256) void k_fuse(
        const float* __restrict__ l,
        const float* __restrict__ gsum,
        const float* __restrict__ fw1, const float* __restrict__ fb1,
        const float* __restrict__ fw2, const float* __restrict__ fb2,
        float* __restrict__ ysA, float* __restrict__ xsA) {
    int p = blockIdx.x * blockDim.x + threadIdx.x;
    if (p >= NPIX) return;
    int b = p / HWP;
    int rem = p % HWP;
    int y = rem / WW;
    int xx = rem % WW;

    float f[32];
#pragma unroll
    for (int o = 0; o < 32; ++o) f[o] = fb1[o];

    const float* lb_ = l + (size_t)b * 32 * HWP;
#pragma unroll
    for (int kh = 0; kh < 3; ++kh) {
#pragma unroll
        for (int kw = 0; kw < 3; ++kw) {
            int yy = y + kh - 1, xw = xx + kw - 1;
            if (yy < 0 || yy >= HH || xw < 0 || xw >= WW) continue;
            int k = kh * 3 + kw;
#pragma unroll
            for (int o = 0; o < 32; ++o) f[o] += gsum[(b * 32 + o) * 9 + k];
            int off = yy * WW + xw;
            for (int cl = 0; cl < 32; ++cl) {
                float t = lb_[cl * HWP + off];
                const float* w = fw1 + (32 + cl) * 9 + k;
#pragma unroll
                for (int o = 0; o < 32; ++o) f[o] += t * w[o * 576];
            }
        }
    }
#pragma unroll
    for (int o = 0; o < 32; ++o) f[o] = fmaxf(f[o], 0.f);

#pragma unroll
    for (int k = 0; k < 9; ++k) {
        float sy = fb2[2 * k], sx = fb2[2 * k + 1];
#pragma unroll
        for (int o = 0; o < 32; ++o) {
            sy += fw2[(2 * k) * 32 + o] * f[o];
            sx += fw2[(2 * k + 1) * 32 + o] * f[o];
        }
        ysA[(size_t)k * NPIX + p] = (float)(y + k / 3 - 1) + sy;
        xsA[(size_t)k * NPIX + p] = (float)(xx + k % 3 - 1) + sx;
    }
}

// ---------------------------------------------------------------------------
// K4: deformable conv as tiled implicit GEMM.
// Block = 256 thr = 64 px x 64 outs. Per k-tap: stage V[ci][px] (bilinear
// samples, gathered once per block) and W_k[ci][o] in LDS, then 4x4/thread
// register-tile GEMM over ci.
// ---------------------------------------------------------------------------
__global__ __launch_bounds__(256) void k_deform(
        const float* __restrict__ x,
        const float* __restrict__ cwT, const float* __restrict__ cb,
        const float* __restrict__ ysA, const float* __restrict__ xsA,
        const float* __restrict__ mA, float* __restrict__ out) {
    __shared__ float Vs[64 * 64];
    __shared__ float Ws[64 * 64];
    __shared__ float4 cf[64];
    __shared__ int4  ig[64];

    int tid = threadIdx.x;
    int p0 = blockIdx.x * 64;
    int b = p0 / HWP;
    int rem0 = p0 % HWP;          // HWP % 64 == 0 -> block stays in one image
    const float* xb = x + (size_t)b * CC * HWP;

    int pxg4 = (tid & 15) * 4;    // this thread's 4 pixels
    int og4 = (tid >> 4) * 4;     // this thread's 4 output channels

    float4 a0, a1, a2, a3;        // o-major: aj = acc for o=og4+j over 4 px
    a0.x = a0.y = a0.z = a0.w = cb[og4 + 0];
    a1.x = a1.y = a1.z = a1.w = cb[og4 + 1];
    a2.x = a2.y = a2.z = a2.w = cb[og4 + 2];
    a3.x = a3.y = a3.z = a3.w = cb[og4 + 3];

    for (int k = 0; k < 9; ++k) {
        __syncthreads();   // prev GEMM done before overwriting Ws/cf/ig
        if (tid < 64) {
            int p = p0 + tid;
            float ys = ysA[(size_t)k * NPIX + p];
            float xs = xsA[(size_t)k * NPIX + p];
            float mk = mA[(size_t)k * NPIX + p];
            float y0f = floorf(ys), x0f = floorf(xs);
            int y0 = (int)y0f, x0 = (int)x0f;
            float wy = ys - y0f, wx = xs - x0f;
            float c00 = (1.f - wy) * (1.f - wx) * mk;
            float c01 = (1.f - wy) * wx * mk;
            float c10 = wy * (1.f - wx) * mk;
            float c11 = wy * wx * mk;
            bool vy0 = (y0 >= 0) && (y0 < HH);
            bool vy1 = (y0 + 1 >= 0) && (y0 + 1 < HH);
            bool vx0 = (x0 >= 0) && (x0 < WW);
            bool vx1 = (x0 + 1 >= 0) && (x0 + 1 < WW);
            c00 = (vy0 && vx0) ? c00 : 0.f;
            c01 = (vy0 && vx1) ? c01 : 0.f;
            c10 = (vy1 && vx0) ? c10 : 0.f;
            c11 = (vy1 && vx1) ? c11 : 0.f;
            int yc0 = min(max(y0, 0), HH - 1), yc1 = min(max(y0 + 1, 0), HH - 1);
            int xc0 = min(max(x0, 0), WW - 1), xc1 = min(max(x0 + 1, 0), WW - 1);
            cf[tid] = make_float4(c00, c01, c10, c11);
            ig[tid] = make_int4(yc0 * WW + xc0, yc0 * WW + xc1,
                                yc1 * WW + xc0, yc1 * WW + xc1);
        }
        // stage W_k: 4096 floats, coalesced from pre-transposed cwT
        {
            const float4* wsrc = (const float4*)(cwT + (size_t)k * 4096);
            float4* wdst = (float4*)Ws;
#pragma unroll
            for (int q = 0; q < 4; ++q) wdst[q * 256 + tid] = wsrc[q * 256 + tid];
        }
        __syncthreads();
        // stage V: chunk c -> px = c&63, ci0 = (c>>6)*4 (coef loaded once/chunk)
#pragma unroll
        for (int q = 0; q < 4; ++q) {
            int c = q * 256 + tid;
            int px = c & 63;
            int ci0 = (c >> 6) * 4;
            float4 cc = cf[px];
            int4 ii = ig[px];
#pragma unroll
            for (int j = 0; j < 4; ++j) {
                const float* xp = xb + (size_t)(ci0 + j) * HWP;
                float v = cc.x * xp[ii.x] + cc.y * xp[ii.y] +
                          cc.z * xp[ii.z] + cc.w * xp[ii.w];
                Vs[(ci0 + j) * 64 + px] = v;
            }
        }
        __syncthreads();
        // GEMM: acc[o][px] += V[ci][px] * W[ci][o]
#pragma unroll 8
        for (int ci = 0; ci < 64; ++ci) {
            float4 v = *(const float4*)&Vs[ci * 64 + pxg4];
            float4 w = *(const float4*)&Ws[ci * 64 + og4];
            a0.x += v.x * w.x; a0.y += v.y * w.x; a0.z += v.z * w.x; a0.w += v.w * w.x;
            a1.x += v.x * w.y; a1.y += v.y * w.y; a1.z += v.z * w.y; a1.w += v.w * w.y;
            a2.x += v.x * w.z; a2.y += v.y * w.z; a2.z += v.z * w.z; a2.w += v.w * w.z;
            a3.x += v.x * w.w; a3.y += v.y * w.w; a3.z += v.z * w.w; a3.w += v.w * w.w;
        }
    }

    float* ob = out + ((size_t)b * OO + og4) * HWP + rem0 + pxg4;
    *(float4*)(ob)            = a0;
    *(float4*)(ob + HWP)      = a1;
    *(float4*)(ob + 2 * HWP)  = a2;
    *(float4*)(ob + 3 * HWP)  = a3;
}

// ---------------------------------------------------------------------------
extern "C" void kernel_launch(void* const* d_in, const int* in_sizes, int n_in,
                              void* d_out, int out_size, void* d_ws, size_t ws_size,
                              hipStream_t stream) {
    const float* x   = (const float*)d_in[0];
    const float* sb  = (const float*)d_in[1];
    const float* gw1 = (const float*)d_in[2];
    const float* gb1 = (const float*)d_in[3];
    const float* gw2 = (const float*)d_in[4];
    const float* gb2 = (const float*)d_in[5];
    const float* lw1 = (const float*)d_in[6];
    const float* lb1 = (const float*)d_in[7];
    const float* lw2 = (const float*)d_in[8];
    const float* lb2 = (const float*)d_in[9];
    const float* fw1 = (const float*)d_in[10];
    const float* fb1 = (const float*)d_in[11];
    const float* fw2 = (const float*)d_in[12];
    const float* fb2 = (const float*)d_in[13];
    const float* mw  = (const float*)d_in[14];
    const float* mb  = (const float*)d_in[15];
    const float* cw  = (const float*)d_in[16];
    const float* cb  = (const float*)d_in[17];
    float* out = (float*)d_out;

    float* gsum = (float*)d_ws;               // 1152
    float* cwT  = gsum + 1152;                // 36864
    float* marr = cwT + 36864;                // 9*NPIX
    float* ysA  = marr + 9 * (size_t)NPIX;    // 9*NPIX
    float* xsA  = ysA + 9 * (size_t)NPIX;     // 9*NPIX
    float* lbuf = xsA + 9 * (size_t)NPIX;     // 32*NPIX  (~27.8 MB total)

    k_glob<<<1, 128, 0, stream>>>(sb, gw1, gb1, gw2, gb2, fw1, gsum);
    k_wt<<<(9 * 64 * 64 + 255) / 256, 256, 0, stream>>>(cw, cwT);
    k_locmask<<<(NPIX + 255) / 256, 256, 0, stream>>>(x, lw1, lb1, lw2, lb2,
                                                      mw, mb, lbuf, marr);
    k_fuse<<<(NPIX + 255) / 256, 256, 0, stream>>>(lbuf, gsum, fw1, fb1,
                                                   fw2, fb2, ysA, xsA);
    k_deform<<<NPIX / 64, 256, 0, stream>>>(x, cwT, cb, ysA, xsA, marr, out);
}

// Round 3
// 473.420 us; speedup vs baseline: 1.8353x; 1.5834x over previous
//
#include <hip/hip_runtime.h>
#include <hip/hip_bf16.h>
#include <math.h>

#define BB 4
#define CC 64
#define OO 64
#define HH 96
#define WW 320
#define HWP (HH*WW)   // 30720
#define NPIX (BB*HWP) // 122880

typedef __attribute__((ext_vector_type(8))) short bf16x8;
typedef __attribute__((ext_vector_type(4))) float f32x4;

__device__ inline unsigned short f2bf(float f) {
    unsigned int u = __float_as_uint(f);
    u = (u + 0x7FFFu + ((u >> 16) & 1u)) >> 16;
    return (unsigned short)u;
}
__device__ inline float bf2f(unsigned short s) {
    return __uint_as_float(((unsigned int)s) << 16);
}

// ---------------------------------------------------------------------------
// K1: global MLP -> g (B,32), Gsum[b][o][k] = sum_ci g[b,ci]*fuse_w1[o,ci,k]
// ---------------------------------------------------------------------------
__global__ void k_glob(const float* __restrict__ sb,
                       const float* __restrict__ gw1, const float* __restrict__ gb1,
                       const float* __restrict__ gw2, const float* __restrict__ gb2,
                       const float* __restrict__ fw1,
                       float* __restrict__ gsum) {
    __shared__ float g_s[BB * 32];
    int tid = threadIdx.x;  // 128 threads
    if (tid < 128) {
        int b = tid >> 5, i = tid & 31;
        float b0 = sb[b * 5 + 4] - sb[b * 5 + 2];
        float b1 = sb[b * 5 + 3] - sb[b * 5 + 1];
        float acc = gb2[i];
        for (int j = 0; j < 64; ++j) {
            float h1 = b0 * gw1[j * 2 + 0] + b1 * gw1[j * 2 + 1] + gb1[j];
            h1 = fmaxf(h1, 0.f);
            acc += gw2[i * 64 + j] * h1;
        }
        g_s[b * 32 + i] = acc;
    }
    __syncthreads();
    for (int e = tid; e < BB * 32 * 9; e += blockDim.x) {
        int b = e / 288, r = e % 288, o = r / 9, k = r % 9;
        float s = 0.f;
        for (int ci = 0; ci < 32; ++ci)
            s += g_s[b * 32 + ci] * fw1[o * 576 + ci * 9 + k];
        gsum[e] = s;
    }
}

// ---------------------------------------------------------------------------
// K_wt: conv_w [o][ci][k] -> cwT bf16 [k][o][ci]  (A-operand source)
// ---------------------------------------------------------------------------
__global__ void k_wt(const float* __restrict__ cw, unsigned short* __restrict__ cwT) {
    int e = blockIdx.x * 256 + threadIdx.x;
    if (e >= 9 * 64 * 64) return;
    int k = e >> 12;
    int r = e & 4095;
    int o = r >> 6;
    int ci = r & 63;
    cwT[e] = f2bf(cw[o * 576 + ci * 9 + k]);
}

// ---------------------------------------------------------------------------
// K_xT: NCHW f32 -> NHWC bf16 (xT[p*64+ci]); 64px x 64ci LDS-tiled transpose
// ---------------------------------------------------------------------------
__global__ __launch_bounds__(256) void k_xT(const float* __restrict__ x,
                                            unsigned short* __restrict__ xT) {
    __shared__ unsigned short Ls[64 * 66];
    int tid = threadIdx.x;
    int p0 = blockIdx.x * 64;
    int b = p0 / HWP;
    int rem0 = p0 % HWP;
    int px = tid & 63;
    int g4 = tid >> 6;   // 0..3
    const float* xb = x + (size_t)b * CC * HWP + rem0;
#pragma unroll
    for (int it = 0; it < 16; ++it) {
        int ci = it * 4 + g4;
        Ls[px * 66 + ci] = f2bf(xb[(size_t)ci * HWP + px]);
    }
    __syncthreads();
#pragma unroll
    for (int it = 0; it < 16; ++it) {
        int p = it * 4 + g4;
        xT[(size_t)(p0 + p) * 64 + px] = Ls[p * 66 + px];
    }
}

// ---------------------------------------------------------------------------
// K2: fused loc path + mask conv (NCHW, coalesced over px)
// ---------------------------------------------------------------------------
__global__ __launch_bounds__(256) void k_locmask(
        const float* __restrict__ x,
        const float* __restrict__ lw1, const float* __restrict__ lb1,
        const float* __restrict__ lw2, const float* __restrict__ lb2,
        const float* __restrict__ mw, const float* __restrict__ mb,
        float* __restrict__ lout, float* __restrict__ mout) {
    int p = blockIdx.x * blockDim.x + threadIdx.x;
    if (p >= NPIX) return;
    int b = p / HWP;
    int rem = p % HWP;
    int y = rem / WW;
    int xx = rem % WW;

    float la[32];
#pragma unroll
    for (int o = 0; o < 32; ++o) la[o] = lb1[o];
    float ma[9];
#pragma unroll
    for (int j = 0; j < 9; ++j) ma[j] = mb[j];

    const float* xb = x + (size_t)b * CC * HWP;
    for (int ci = 0; ci < CC; ++ci) {
        const float* xp = xb + ci * HWP;
        float t[9];
#pragma unroll
        for (int kh = 0; kh < 3; ++kh)
#pragma unroll
            for (int kw = 0; kw < 3; ++kw) {
                int yy = y + kh - 1, xw = xx + kw - 1;
                bool v = (yy >= 0) && (yy < HH) && (xw >= 0) && (xw < WW);
                t[kh * 3 + kw] = v ? xp[yy * WW + xw] : 0.f;
            }
        const float* wp = lw1 + ci * 9;
#pragma unroll
        for (int o = 0; o < 32; ++o) {
            const float* w = wp + o * 576;
            float s = la[o];
#pragma unroll
            for (int k = 0; k < 9; ++k) s += t[k] * w[k];
            la[o] = s;
        }
        const float* wm = mw + ci * 9;
#pragma unroll
        for (int j = 0; j < 9; ++j) {
            const float* w = wm + j * 576;
            float s = ma[j];
#pragma unroll
            for (int k = 0; k < 9; ++k) s += t[k] * w[k];
            ma[j] = s;
        }
    }
#pragma unroll
    for (int o = 0; o < 32; ++o) la[o] = fmaxf(la[o], 0.f);

#pragma unroll
    for (int o2 = 0; o2 < 32; ++o2) {
        float s = lb2[o2];
#pragma unroll
        for (int o = 0; o < 32; ++o) s += lw2[o2 * 32 + o] * la[o];
        lout[((size_t)b * 32 + o2) * HWP + rem] = s;
    }
#pragma unroll
    for (int j = 0; j < 9; ++j)
        mout[(size_t)j * NPIX + p] = 1.f / (1.f + __expf(-ma[j]));
}

// ---------------------------------------------------------------------------
// K3: fuse conv (Gsum for g-channels) -> f -> offsets -> sample coords
// ---------------------------------------------------------------------------
__global__ __launch_bounds__(256) void k_fuse(
        const float* __restrict__ l,
        const float* __restrict__ gsum,
        const float* __restrict__ fw1, const float* __restrict__ fb1,
        const float* __restrict__ fw2, const float* __restrict__ fb2,
        float* __restrict__ ysA, float* __restrict__ xsA) {
    int p = blockIdx.x * blockDim.x + threadIdx.x;
    if (p >= NPIX) return;
    int b = p / HWP;
    int rem = p % HWP;
    int y = rem / WW;
    int xx = rem % WW;

    float f[32];
#pragma unroll
    for (int o = 0; o < 32; ++o) f[o] = fb1[o];

    const float* lb_ = l + (size_t)b * 32 * HWP;
#pragma unroll
    for (int kh = 0; kh < 3; ++kh) {
#pragma unroll
        for (int kw = 0; kw < 3; ++kw) {
            int yy = y + kh - 1, xw = xx + kw - 1;
            if (yy < 0 || yy >= HH || xw < 0 || xw >= WW) continue;
            int k = kh * 3 + kw;
#pragma unroll
            for (int o = 0; o < 32; ++o) f[o] += gsum[(b * 32 + o) * 9 + k];
            int off = yy * WW + xw;
            for (int cl = 0; cl < 32; ++cl) {
                float t = lb_[cl * HWP + off];
                const float* w = fw1 + (32 + cl) * 9 + k;
#pragma unroll
                for (int o = 0; o < 32; ++o) f[o] += t * w[o * 576];
            }
        }
    }
#pragma unroll
    for (int o = 0; o < 32; ++o) f[o] = fmaxf(f[o], 0.f);

#pragma unroll
    for (int k = 0; k < 9; ++k) {
        float sy = fb2[2 * k], sx = fb2[2 * k + 1];
#pragma unroll
        for (int o = 0; o < 32; ++o) {
            sy += fw2[(2 * k) * 32 + o] * f[o];
            sx += fw2[(2 * k + 1) * 32 + o] * f[o];
        }
        ysA[(size_t)k * NPIX + p] = (float)(y + k / 3 - 1) + sy;
        xsA[(size_t)k * NPIX + p] = (float)(xx + k % 3 - 1) + sx;
    }
}

// ---------------------------------------------------------------------------
// K4: deformable conv, MFMA implicit GEMM.
// Block = 256 thr (4 waves) = 64 px x 64 o tile. Per tap: stage
// V[px][ci] (bf16, bilinear from NHWC-bf16 xT) + W_k[o][ci] (bf16) in LDS,
// then 4x mfma_f32_16x16x32_bf16 per wave per k-half.
// A = W (m=o), B = V (n=px)  =>  D rows = o, cols = px (coalesced stores).
// ---------------------------------------------------------------------------
__global__ __launch_bounds__(256) void k_deform(
        const unsigned short* __restrict__ xT,
        const unsigned short* __restrict__ cwT, const float* __restrict__ cb,
        const float* __restrict__ ysA, const float* __restrict__ xsA,
        const float* __restrict__ mA, float* __restrict__ out) {
    __shared__ unsigned short Vs[64 * 72];   // [px][ci] pad->72
    __shared__ unsigned short Ws[64 * 72];   // [o][ci]  pad->72
    __shared__ float4 cfA[9 * 64];
    __shared__ int4   igA[9 * 64];

    int tid = threadIdx.x;
    int p0 = blockIdx.x * 64;
    int b = p0 / HWP;
    int rem0 = p0 % HWP;
    const unsigned short* xTb = xT + (size_t)b * HWP * 64;

    // precompute bilinear coefs + (pre-scaled) corner indices, all 9 taps
    for (int e = tid; e < 9 * 64; e += 256) {
        int k = e / 64, px = e % 64;
        int p = p0 + px;
        float ys = ysA[(size_t)k * NPIX + p];
        float xs = xsA[(size_t)k * NPIX + p];
        float mk = mA[(size_t)k * NPIX + p];
        float y0f = floorf(ys), x0f = floorf(xs);
        int y0 = (int)y0f, x0 = (int)x0f;
        float wy = ys - y0f, wx = xs - x0f;
        float c00 = (1.f - wy) * (1.f - wx) * mk;
        float c01 = (1.f - wy) * wx * mk;
        float c10 = wy * (1.f - wx) * mk;
        float c11 = wy * wx * mk;
        bool vy0 = (y0 >= 0) && (y0 < HH);
        bool vy1 = (y0 + 1 >= 0) && (y0 + 1 < HH);
        bool vx0 = (x0 >= 0) && (x0 < WW);
        bool vx1 = (x0 + 1 >= 0) && (x0 + 1 < WW);
        c00 = (vy0 && vx0) ? c00 : 0.f;
        c01 = (vy0 && vx1) ? c01 : 0.f;
        c10 = (vy1 && vx0) ? c10 : 0.f;
        c11 = (vy1 && vx1) ? c11 : 0.f;
        int yc0 = min(max(y0, 0), HH - 1), yc1 = min(max(y0 + 1, 0), HH - 1);
        int xc0 = min(max(x0, 0), WW - 1), xc1 = min(max(x0 + 1, 0), WW - 1);
        cfA[e] = make_float4(c00, c01, c10, c11);
        igA[e] = make_int4((yc0 * WW + xc0) * 64, (yc0 * WW + xc1) * 64,
                           (yc1 * WW + xc0) * 64, (yc1 * WW + xc1) * 64);
    }

    int lane = tid & 63;
    int wv = tid >> 6;          // wave id 0..3
    int m0 = wv * 16;           // o-tile base
    int lr = lane & 15;
    int lq = lane >> 4;         // 0..3

    f32x4 cini;
    cini[0] = cb[m0 + lq * 4 + 0];
    cini[1] = cb[m0 + lq * 4 + 1];
    cini[2] = cb[m0 + lq * 4 + 2];
    cini[3] = cb[m0 + lq * 4 + 3];
    f32x4 acc[4];
#pragma unroll
    for (int t = 0; t < 4; ++t) acc[t] = cini;

    int sgc = tid & 15;         // ci-group for staging
    int sci0 = sgc * 4;
    int spx = tid >> 4;         // base px (0..15)

    for (int k = 0; k < 9; ++k) {
        __syncthreads();        // prev GEMM done (also covers cfA/igA init)
        // stage W_k: 4096 bf16, coalesced float4 copy into padded rows
#pragma unroll
        for (int c = tid; c < 512; c += 256) {
            int o = c >> 3, g = c & 7;
            *(float4*)&Ws[o * 72 + g * 8] = ((const float4*)(cwT + (size_t)k * 4096))[c];
        }
        // stage V: thread -> (px, 4 channels); corner rows are contiguous in xT
#pragma unroll
        for (int q = 0; q < 4; ++q) {
            int px = q * 16 + spx;
            float4 cc = cfA[k * 64 + px];
            int4 ii = igA[k * 64 + px];
            ushort4 u00 = *(const ushort4*)&xTb[ii.x + sci0];
            ushort4 u01 = *(const ushort4*)&xTb[ii.y + sci0];
            ushort4 u10 = *(const ushort4*)&xTb[ii.z + sci0];
            ushort4 u11 = *(const ushort4*)&xTb[ii.w + sci0];
            ushort4 r;
            r.x = f2bf(cc.x * bf2f(u00.x) + cc.y * bf2f(u01.x) + cc.z * bf2f(u10.x) + cc.w * bf2f(u11.x));
            r.y = f2bf(cc.x * bf2f(u00.y) + cc.y * bf2f(u01.y) + cc.z * bf2f(u10.y) + cc.w * bf2f(u11.y));
            r.z = f2bf(cc.x * bf2f(u00.z) + cc.y * bf2f(u01.z) + cc.z * bf2f(u10.z) + cc.w * bf2f(u11.z));
            r.w = f2bf(cc.x * bf2f(u00.w) + cc.y * bf2f(u01.w) + cc.z * bf2f(u10.w) + cc.w * bf2f(u11.w));
            *(ushort4*)&Vs[px * 72 + sci0] = r;
        }
        __syncthreads();
        // MFMA: A-frag from Ws (o-tile fixed per wave), B-frags over 4 px-tiles
        bf16x8 a0 = *(const bf16x8*)&Ws[(m0 + lr) * 72 + lq * 8];
        bf16x8 a1 = *(const bf16x8*)&Ws[(m0 + lr) * 72 + 32 + lq * 8];
#pragma unroll
        for (int t = 0; t < 4; ++t) {
            bf16x8 b0 = *(const bf16x8*)&Vs[(t * 16 + lr) * 72 + lq * 8];
            bf16x8 b1 = *(const bf16x8*)&Vs[(t * 16 + lr) * 72 + 32 + lq * 8];
            acc[t] = __builtin_amdgcn_mfma_f32_16x16x32_bf16(a0, b0, acc[t], 0, 0, 0);
            acc[t] = __builtin_amdgcn_mfma_f32_16x16x32_bf16(a1, b1, acc[t], 0, 0, 0);
        }
    }

    // D[m=o][n=px]: row = lq*4+r, col = lr  -> coalesced over px
#pragma unroll
    for (int t = 0; t < 4; ++t) {
#pragma unroll
        for (int r = 0; r < 4; ++r) {
            int o = m0 + lq * 4 + r;
            out[(size_t)(b * 64 + o) * HWP + rem0 + t * 16 + lr] = acc[t][r];
        }
    }
}

// ---------------------------------------------------------------------------
extern "C" void kernel_launch(void* const* d_in, const int* in_sizes, int n_in,
                              void* d_out, int out_size, void* d_ws, size_t ws_size,
                              hipStream_t stream) {
    const float* x   = (const float*)d_in[0];
    const float* sb  = (const float*)d_in[1];
    const float* gw1 = (const float*)d_in[2];
    const float* gb1 = (const float*)d_in[3];
    const float* gw2 = (const float*)d_in[4];
    const float* gb2 = (const float*)d_in[5];
    const float* lw1 = (const float*)d_in[6];
    const float* lb1 = (const float*)d_in[7];
    const float* lw2 = (const float*)d_in[8];
    const float* lb2 = (const float*)d_in[9];
    const float* fw1 = (const float*)d_in[10];
    const float* fb1 = (const float*)d_in[11];
    const float* fw2 = (const float*)d_in[12];
    const float* fb2 = (const float*)d_in[13];
    const float* mw  = (const float*)d_in[14];
    const float* mb  = (const float*)d_in[15];
    const float* cw  = (const float*)d_in[16];
    const float* cb  = (const float*)d_in[17];
    float* out = (float*)d_out;

    float* gsum = (float*)d_ws;                               // 1152 f
    unsigned short* cwT = (unsigned short*)(gsum + 1152);     // 36864 us (18432 f)
    float* marr = gsum + 1152 + 18432;                        // 9*NPIX f
    float* ysA  = marr + 9 * (size_t)NPIX;                    // 9*NPIX f
    float* xsA  = ysA + 9 * (size_t)NPIX;                     // 9*NPIX f
    float* lbuf = xsA + 9 * (size_t)NPIX;                     // 32*NPIX f
    unsigned short* xT = (unsigned short*)lbuf;               // aliases lbuf (dead after k_fuse)

    k_glob<<<1, 128, 0, stream>>>(sb, gw1, gb1, gw2, gb2, fw1, gsum);
    k_wt<<<(9 * 64 * 64 + 255) / 256, 256, 0, stream>>>(cw, cwT);
    k_locmask<<<(NPIX + 255) / 256, 256, 0, stream>>>(x, lw1, lb1, lw2, lb2,
                                                      mw, mb, lbuf, marr);
    k_fuse<<<(NPIX + 255) / 256, 256, 0, stream>>>(lbuf, gsum, fw1, fb1,
                                                   fw2, fb2, ysA, xsA);
    k_xT<<<NPIX / 64, 256, 0, stream>>>(x, xT);               // after k_fuse: xT aliases lbuf
    k_deform<<<NPIX / 64, 256, 0, stream>>>(xT, cwT, cb, ysA, xsA, marr, out);
}

// Round 4
// 217.435 us; speedup vs baseline: 3.9960x; 2.1773x over previous
//
#include <hip/hip_runtime.h>
#include <hip/hip_bf16.h>
#include <math.h>

#define BB 4
#define CC 64
#define OO 64
#define HH 96
#define WW 320
#define HWP (HH*WW)   // 30720
#define NPIX (BB*HWP) // 122880

typedef __attribute__((ext_vector_type(8))) short bf16x8;
typedef __attribute__((ext_vector_type(4))) float f32x4;

__device__ inline unsigned short f2bf(float f) {
    unsigned int u = __float_as_uint(f);
    u = (u + 0x7FFFu + ((u >> 16) & 1u)) >> 16;
    return (unsigned short)u;
}
__device__ inline float bf2f(unsigned short s) {
    return __uint_as_float(((unsigned int)s) << 16);
}

// ---------------------------------------------------------------------------
// K1: global MLP -> g (B,32), Gsum[b][o][k] = sum_ci g[b,ci]*fuse_w1[o,ci,k]
// ---------------------------------------------------------------------------
__global__ void k_glob(const float* __restrict__ sb,
                       const float* __restrict__ gw1, const float* __restrict__ gb1,
                       const float* __restrict__ gw2, const float* __restrict__ gb2,
                       const float* __restrict__ fw1,
                       float* __restrict__ gsum) {
    __shared__ float g_s[BB * 32];
    int tid = threadIdx.x;  // 128 threads
    if (tid < 128) {
        int b = tid >> 5, i = tid & 31;
        float b0 = sb[b * 5 + 4] - sb[b * 5 + 2];
        float b1 = sb[b * 5 + 3] - sb[b * 5 + 1];
        float acc = gb2[i];
        for (int j = 0; j < 64; ++j) {
            float h1 = b0 * gw1[j * 2 + 0] + b1 * gw1[j * 2 + 1] + gb1[j];
            h1 = fmaxf(h1, 0.f);
            acc += gw2[i * 64 + j] * h1;
        }
        g_s[b * 32 + i] = acc;
    }
    __syncthreads();
    for (int e = tid; e < BB * 32 * 9; e += blockDim.x) {
        int b = e / 288, r = e % 288, o = r / 9, k = r % 9;
        float s = 0.f;
        for (int ci = 0; ci < 32; ++ci)
            s += g_s[b * 32 + ci] * fw1[o * 576 + ci * 9 + k];
        gsum[e] = s;
    }
}

// ---------------------------------------------------------------------------
// K_prep: all bf16 weight repacks in one launch.
//  cwT  [9][64 o][64 ci]  <- conv_w
//  Wlm  [9][48 r][64 ci]  <- rows 0-31 loc_w1, 32-40 mask_w, 41-47 zero
//  lw2T [32][32]          <- loc_w2
//  Wf   [9][32 o][32 cl]  <- fuse_w1 l-channels
//  fw2A [32][32]          <- rows 0-17 fuse_w2, rest zero
// ---------------------------------------------------------------------------
#define PREP_N (36864 + 27648 + 1024 + 9216 + 1024)
__global__ void k_prep(const float* __restrict__ cw,
                       const float* __restrict__ lw1, const float* __restrict__ mw,
                       const float* __restrict__ lw2,
                       const float* __restrict__ fw1, const float* __restrict__ fw2,
                       unsigned short* __restrict__ cwT,
                       unsigned short* __restrict__ Wlm,
                       unsigned short* __restrict__ lw2T,
                       unsigned short* __restrict__ Wf,
                       unsigned short* __restrict__ fw2A) {
    int e = blockIdx.x * 256 + threadIdx.x;
    if (e < 36864) {
        int k = e >> 12, r = e & 4095, o = r >> 6, ci = r & 63;
        cwT[e] = f2bf(cw[o * 576 + ci * 9 + k]);
        return;
    }
    e -= 36864;
    if (e < 27648) {
        int k = e / 3072, r = e % 3072, row = r >> 6, ci = r & 63;
        float v = 0.f;
        if (row < 32) v = lw1[row * 576 + ci * 9 + k];
        else if (row < 41) v = mw[(row - 32) * 576 + ci * 9 + k];
        Wlm[e] = f2bf(v);
        return;
    }
    e -= 27648;
    if (e < 1024) { lw2T[e] = f2bf(lw2[e]); return; }
    e -= 1024;
    if (e < 9216) {
        int k = e >> 10, r = e & 1023, o = r >> 5, cl = r & 31;
        Wf[e] = f2bf(fw1[o * 576 + (32 + cl) * 9 + k]);
        return;
    }
    e -= 9216;
    if (e < 1024) {
        int m = e >> 5, ci = e & 31;
        fw2A[e] = f2bf(m < 18 ? fw2[m * 32 + ci] : 0.f);
    }
}

// ---------------------------------------------------------------------------
// K_xT: NCHW f32 -> NHWC bf16 (xT[p*64+ci]); 64px x 64ci LDS-tiled transpose
// ---------------------------------------------------------------------------
__global__ __launch_bounds__(256) void k_xT(const float* __restrict__ x,
                                            unsigned short* __restrict__ xT) {
    __shared__ unsigned short Ls[64 * 66];
    int tid = threadIdx.x;
    int p0 = blockIdx.x * 64;
    int b = p0 / HWP;
    int rem0 = p0 % HWP;
    int px = tid & 63;
    int g4 = tid >> 6;   // 0..3
    const float* xb = x + (size_t)b * CC * HWP + rem0;
#pragma unroll
    for (int it = 0; it < 16; ++it) {
        int ci = it * 4 + g4;
        Ls[px * 66 + ci] = f2bf(xb[(size_t)ci * HWP + px]);
    }
    __syncthreads();
#pragma unroll
    for (int it = 0; it < 16; ++it) {
        int p = it * 4 + g4;
        xT[(size_t)(p0 + p) * 64 + px] = Ls[p * 66 + px];
    }
}

// ---------------------------------------------------------------------------
// K2: loc+mask as MFMA implicit GEMM. Block = 256 thr = 128 px.
// GEMM1: M=48 (32 loc1 + 9 mask + pad), K=576 (9 taps x 64 ci), N=128 px.
// Then relu -> LDS, GEMM2: l = lw2 (32x32) x relu(l1). mask -> sigmoid -> bf16.
// Outputs: lT NHWC bf16 [p][32], mbuf bf16 [k][p].
// ---------------------------------------------------------------------------
__global__ __launch_bounds__(256) void k_locmask(
        const unsigned short* __restrict__ xT,
        const unsigned short* __restrict__ Wlm,
        const unsigned short* __restrict__ lw2T,
        const float* __restrict__ lb1, const float* __restrict__ lb2,
        const float* __restrict__ mb,
        unsigned short* __restrict__ lT, unsigned short* __restrict__ mbuf) {
    __shared__ unsigned short Vs[128 * 72];
    __shared__ unsigned short Ws[48 * 72];
    __shared__ unsigned short VsL[128 * 40];
    __shared__ unsigned short W2[32 * 40];

    int tid = threadIdx.x;
    int p0 = blockIdx.x * 128;
    int rem0 = p0 % HWP;

    int lane = tid & 63, wv = tid >> 6;
    int lr = lane & 15, lq = lane >> 4;
    int n0 = wv * 32;

    int spx = tid >> 1;      // staging pixel 0..127
    int shf = tid & 1;       // ci half
    int sy = (rem0 + spx) / WW;
    int sx = (rem0 + spx) % WW;

    f32x4 acc[3][2];
#pragma unroll
    for (int mt = 0; mt < 3; ++mt)
#pragma unroll
        for (int t = 0; t < 2; ++t) acc[mt][t] = (f32x4){0.f, 0.f, 0.f, 0.f};

    for (int k = 0; k < 9; ++k) {
        int dy = k / 3 - 1, dx = k % 3 - 1;
        __syncthreads();
        // stage A: 48 rows x 64 ci = 384 16B chunks
#pragma unroll
        for (int c = tid; c < 384; c += 256) {
            int row = c >> 3, g = c & 7;
            *(float4*)&Ws[row * 72 + g * 8] =
                *(const float4*)&Wlm[((size_t)k * 48 + row) * 64 + g * 8];
        }
        // stage B: this thread's (px, ci-half) = 4 x 16B
        {
            int yy = sy + dy, xw = sx + dx;
            bool valid = (yy >= 0) && (yy < HH) && (xw >= 0) && (xw < WW);
            unsigned short* dst = &Vs[spx * 72 + shf * 32];
            if (valid) {
                const unsigned short* src =
                    xT + ((size_t)(p0 + spx) + (dy * WW + dx)) * 64 + shf * 32;
#pragma unroll
                for (int j = 0; j < 4; ++j)
                    *(float4*)(dst + j * 8) = *(const float4*)(src + j * 8);
            } else {
                float4 z = {0.f, 0.f, 0.f, 0.f};
#pragma unroll
                for (int j = 0; j < 4; ++j) *(float4*)(dst + j * 8) = z;
            }
        }
        __syncthreads();
#pragma unroll
        for (int h = 0; h < 2; ++h) {
            bf16x8 b0 = *(const bf16x8*)&Vs[(n0 + lr) * 72 + h * 32 + lq * 8];
            bf16x8 b1 = *(const bf16x8*)&Vs[(n0 + 16 + lr) * 72 + h * 32 + lq * 8];
#pragma unroll
            for (int mt = 0; mt < 3; ++mt) {
                bf16x8 a = *(const bf16x8*)&Ws[(mt * 16 + lr) * 72 + h * 32 + lq * 8];
                acc[mt][0] = __builtin_amdgcn_mfma_f32_16x16x32_bf16(a, b0, acc[mt][0], 0, 0, 0);
                acc[mt][1] = __builtin_amdgcn_mfma_f32_16x16x32_bf16(a, b1, acc[mt][1], 0, 0, 0);
            }
        }
    }

    // stage lw2 A while finishing epilogue
#pragma unroll
    for (int c = tid; c < 128; c += 256) {
        int row = c >> 2, g = c & 3;
        *(float4*)&W2[row * 40 + g * 8] = *(const float4*)&lw2T[row * 32 + g * 8];
    }
    // loc1: bias + relu -> VsL[px][m] bf16
#pragma unroll
    for (int mt = 0; mt < 2; ++mt)
#pragma unroll
        for (int t = 0; t < 2; ++t)
#pragma unroll
            for (int r = 0; r < 4; ++r) {
                int m = mt * 16 + lq * 4 + r;
                float v = acc[mt][t][r] + lb1[m];
                VsL[(n0 + t * 16 + lr) * 40 + m] = f2bf(fmaxf(v, 0.f));
            }
    // mask rows (mt=2): sigmoid -> mbuf
#pragma unroll
    for (int t = 0; t < 2; ++t)
#pragma unroll
        for (int r = 0; r < 4; ++r) {
            int j = lq * 4 + r;
            if (j < 9) {
                float v = acc[2][t][r] + mb[j];
                v = 1.f / (1.f + __expf(-v));
                mbuf[(size_t)j * NPIX + p0 + n0 + t * 16 + lr] = f2bf(v);
            }
        }
    __syncthreads();
    // GEMM2: l = lw2 x relu(l1), K=32 (one MFMA step)
    f32x4 acc2[2][2];
#pragma unroll
    for (int mt = 0; mt < 2; ++mt)
#pragma unroll
        for (int t = 0; t < 2; ++t) acc2[mt][t] = (f32x4){0.f, 0.f, 0.f, 0.f};
#pragma unroll
    for (int t = 0; t < 2; ++t) {
        bf16x8 b2 = *(const bf16x8*)&VsL[(n0 + t * 16 + lr) * 40 + lq * 8];
#pragma unroll
        for (int mt = 0; mt < 2; ++mt) {
            bf16x8 a2 = *(const bf16x8*)&W2[(mt * 16 + lr) * 40 + lq * 8];
            acc2[mt][t] = __builtin_amdgcn_mfma_f32_16x16x32_bf16(a2, b2, acc2[mt][t], 0, 0, 0);
        }
    }
    __syncthreads();  // Vs reuse as [px][40] shuffle buffer
#pragma unroll
    for (int mt = 0; mt < 2; ++mt)
#pragma unroll
        for (int t = 0; t < 2; ++t)
#pragma unroll
            for (int r = 0; r < 4; ++r) {
                int m = mt * 16 + lq * 4 + r;
                Vs[(n0 + t * 16 + lr) * 40 + m] = f2bf(acc2[mt][t][r] + lb2[m]);
            }
    __syncthreads();
    // coalesced NHWC store of l
    {
        int px = tid >> 1, hf = tid & 1;
        float4 v0 = *(const float4*)&Vs[px * 40 + hf * 16];
        float4 v1 = *(const float4*)&Vs[px * 40 + hf * 16 + 8];
        unsigned short* dst = lT + (size_t)(p0 + px) * 32 + hf * 16;
        *(float4*)dst = v0;
        *(float4*)(dst + 8) = v1;
    }
}

// ---------------------------------------------------------------------------
// K3: fuse conv as MFMA implicit GEMM. M=32 f, K=288 (9 taps x 32 l-ch), N=128.
// Gsum (g-channel contribution, per-px tap validity) added in epilogue.
// GEMM2: offset = fw2 (18x32 pad 32) x relu(f). Writes ysA/xsA (abs coords).
// ---------------------------------------------------------------------------
__global__ __launch_bounds__(256) void k_fuse(
        const unsigned short* __restrict__ lT,
        const float* __restrict__ gsum,
        const unsigned short* __restrict__ Wf,
        const unsigned short* __restrict__ fw2A,
        const float* __restrict__ fb1, const float* __restrict__ fb2,
        float* __restrict__ ysA, float* __restrict__ xsA) {
    __shared__ unsigned short Vs[128 * 40];
    __shared__ unsigned short Ws[32 * 40];
    __shared__ unsigned short VsF[128 * 40];
    __shared__ unsigned short W2[32 * 40];
    __shared__ float gs[288];

    int tid = threadIdx.x;
    int p0 = blockIdx.x * 128;
    int b = p0 / HWP;
    int rem0 = p0 % HWP;

    int lane = tid & 63, wv = tid >> 6;
    int lr = lane & 15, lq = lane >> 4;
    int n0 = wv * 32;

    int spx = tid >> 1;
    int shf = tid & 1;
    int sy = (rem0 + spx) / WW;
    int sx = (rem0 + spx) % WW;

    for (int e = tid; e < 288; e += 256) gs[e] = gsum[b * 288 + e];

    f32x4 acc[2][2];
#pragma unroll
    for (int mt = 0; mt < 2; ++mt)
#pragma unroll
        for (int t = 0; t < 2; ++t) acc[mt][t] = (f32x4){0.f, 0.f, 0.f, 0.f};

    for (int k = 0; k < 9; ++k) {
        int dy = k / 3 - 1, dx = k % 3 - 1;
        __syncthreads();
#pragma unroll
        for (int c = tid; c < 128; c += 256) {
            int row = c >> 2, g = c & 3;
            *(float4*)&Ws[row * 40 + g * 8] =
                *(const float4*)&Wf[((size_t)k * 32 + row) * 32 + g * 8];
        }
        {
            int yy = sy + dy, xw = sx + dx;
            bool valid = (yy >= 0) && (yy < HH) && (xw >= 0) && (xw < WW);
            unsigned short* dst = &Vs[spx * 40 + shf * 16];
            if (valid) {
                const unsigned short* src =
                    lT + ((size_t)(p0 + spx) + (dy * WW + dx)) * 32 + shf * 16;
                *(float4*)dst = *(const float4*)src;
                *(float4*)(dst + 8) = *(const float4*)(src + 8);
            } else {
                float4 z = {0.f, 0.f, 0.f, 0.f};
                *(float4*)dst = z;
                *(float4*)(dst + 8) = z;
            }
        }
        __syncthreads();
#pragma unroll
        for (int t = 0; t < 2; ++t) {
            bf16x8 bfr = *(const bf16x8*)&Vs[(n0 + t * 16 + lr) * 40 + lq * 8];
#pragma unroll
            for (int mt = 0; mt < 2; ++mt) {
                bf16x8 a = *(const bf16x8*)&Ws[(mt * 16 + lr) * 40 + lq * 8];
                acc[mt][t] = __builtin_amdgcn_mfma_f32_16x16x32_bf16(a, bfr, acc[mt][t], 0, 0, 0);
            }
        }
    }

#pragma unroll
    for (int c = tid; c < 128; c += 256) {
        int row = c >> 2, g = c & 3;
        *(float4*)&W2[row * 40 + g * 8] = *(const float4*)&fw2A[row * 32 + g * 8];
    }
    // epilogue: + fb1 + valid-tap Gsum, relu -> VsF
#pragma unroll
    for (int t = 0; t < 2; ++t) {
        int px = n0 + t * 16 + lr;
        int rem = rem0 + px;
        int y = rem / WW, xx = rem % WW;
        bool vk[9];
#pragma unroll
        for (int k = 0; k < 9; ++k) {
            int yy = y + k / 3 - 1, xw = xx + k % 3 - 1;
            vk[k] = (yy >= 0) && (yy < HH) && (xw >= 0) && (xw < WW);
        }
#pragma unroll
        for (int mt = 0; mt < 2; ++mt)
#pragma unroll
            for (int r = 0; r < 4; ++r) {
                int m = mt * 16 + lq * 4 + r;
                float s = fb1[m];
#pragma unroll
                for (int k = 0; k < 9; ++k)
                    if (vk[k]) s += gs[m * 9 + k];
                float v = acc[mt][t][r] + s;
                VsF[px * 40 + m] = f2bf(fmaxf(v, 0.f));
            }
    }
    __syncthreads();
    f32x4 acc3[2][2];
#pragma unroll
    for (int mt = 0; mt < 2; ++mt)
#pragma unroll
        for (int t = 0; t < 2; ++t) acc3[mt][t] = (f32x4){0.f, 0.f, 0.f, 0.f};
#pragma unroll
    for (int t = 0; t < 2; ++t) {
        bf16x8 b2 = *(const bf16x8*)&VsF[(n0 + t * 16 + lr) * 40 + lq * 8];
#pragma unroll
        for (int mt = 0; mt < 2; ++mt) {
            bf16x8 a2 = *(const bf16x8*)&W2[(mt * 16 + lr) * 40 + lq * 8];
            acc3[mt][t] = __builtin_amdgcn_mfma_f32_16x16x32_bf16(a2, b2, acc3[mt][t], 0, 0, 0);
        }
    }
#pragma unroll
    for (int t = 0; t < 2; ++t) {
        int px = n0 + t * 16 + lr;
        int p = p0 + px;
        int rem = rem0 + px;
        int y = rem / WW, xx = rem % WW;
#pragma unroll
        for (int mt = 0; mt < 2; ++mt)
#pragma unroll
            for (int r = 0; r < 4; ++r) {
                int m = mt * 16 + lq * 4 + r;
                if (m < 18) {
                    int k = m >> 1;
                    float v = acc3[mt][t][r] + fb2[m];
                    if ((m & 1) == 0)
                        ysA[(size_t)k * NPIX + p] = (float)(y + k / 3 - 1) + v;
                    else
                        xsA[(size_t)k * NPIX + p] = (float)(xx + k % 3 - 1) + v;
                }
            }
    }
}

// ---------------------------------------------------------------------------
// K4: deformable conv, MFMA implicit GEMM (as R3, mask now bf16).
// ---------------------------------------------------------------------------
__global__ __launch_bounds__(256) void k_deform(
        const unsigned short* __restrict__ xT,
        const unsigned short* __restrict__ cwT, const float* __restrict__ cb,
        const float* __restrict__ ysA, const float* __restrict__ xsA,
        const unsigned short* __restrict__ mA, float* __restrict__ out) {
    __shared__ unsigned short Vs[64 * 72];   // [px][ci] pad->72
    __shared__ unsigned short Ws[64 * 72];   // [o][ci]  pad->72
    __shared__ float4 cfA[9 * 64];
    __shared__ int4   igA[9 * 64];

    int tid = threadIdx.x;
    int p0 = blockIdx.x * 64;
    int b = p0 / HWP;
    int rem0 = p0 % HWP;
    const unsigned short* xTb = xT + (size_t)b * HWP * 64;

    for (int e = tid; e < 9 * 64; e += 256) {
        int k = e / 64, px = e % 64;
        int p = p0 + px;
        float ys = ysA[(size_t)k * NPIX + p];
        float xs = xsA[(size_t)k * NPIX + p];
        float mk = bf2f(mA[(size_t)k * NPIX + p]);
        float y0f = floorf(ys), x0f = floorf(xs);
        int y0 = (int)y0f, x0 = (int)x0f;
        float wy = ys - y0f, wx = xs - x0f;
        float c00 = (1.f - wy) * (1.f - wx) * mk;
        float c01 = (1.f - wy) * wx * mk;
        float c10 = wy * (1.f - wx) * mk;
        float c11 = wy * wx * mk;
        bool vy0 = (y0 >= 0) && (y0 < HH);
        bool vy1 = (y0 + 1 >= 0) && (y0 + 1 < HH);
        bool vx0 = (x0 >= 0) && (x0 < WW);
        bool vx1 = (x0 + 1 >= 0) && (x0 + 1 < WW);
        c00 = (vy0 && vx0) ? c00 : 0.f;
        c01 = (vy0 && vx1) ? c01 : 0.f;
        c10 = (vy1 && vx0) ? c10 : 0.f;
        c11 = (vy1 && vx1) ? c11 : 0.f;
        int yc0 = min(max(y0, 0), HH - 1), yc1 = min(max(y0 + 1, 0), HH - 1);
        int xc0 = min(max(x0, 0), WW - 1), xc1 = min(max(x0 + 1, 0), WW - 1);
        cfA[e] = make_float4(c00, c01, c10, c11);
        igA[e] = make_int4((yc0 * WW + xc0) * 64, (yc0 * WW + xc1) * 64,
                           (yc1 * WW + xc0) * 64, (yc1 * WW + xc1) * 64);
    }

    int lane = tid & 63;
    int wv = tid >> 6;
    int m0 = wv * 16;
    int lr = lane & 15;
    int lq = lane >> 4;

    f32x4 cini;
    cini[0] = cb[m0 + lq * 4 + 0];
    cini[1] = cb[m0 + lq * 4 + 1];
    cini[2] = cb[m0 + lq * 4 + 2];
    cini[3] = cb[m0 + lq * 4 + 3];
    f32x4 acc[4];
#pragma unroll
    for (int t = 0; t < 4; ++t) acc[t] = cini;

    int sgc = tid & 15;
    int sci0 = sgc * 4;
    int spx = tid >> 4;

    for (int k = 0; k < 9; ++k) {
        __syncthreads();
#pragma unroll
        for (int c = tid; c < 512; c += 256) {
            int o = c >> 3, g = c & 7;
            *(float4*)&Ws[o * 72 + g * 8] = ((const float4*)(cwT + (size_t)k * 4096))[c];
        }
#pragma unroll
        for (int q = 0; q < 4; ++q) {
            int px = q * 16 + spx;
            float4 cc = cfA[k * 64 + px];
            int4 ii = igA[k * 64 + px];
            ushort4 u00 = *(const ushort4*)&xTb[ii.x + sci0];
            ushort4 u01 = *(const ushort4*)&xTb[ii.y + sci0];
            ushort4 u10 = *(const ushort4*)&xTb[ii.z + sci0];
            ushort4 u11 = *(const ushort4*)&xTb[ii.w + sci0];
            ushort4 r;
            r.x = f2bf(cc.x * bf2f(u00.x) + cc.y * bf2f(u01.x) + cc.z * bf2f(u10.x) + cc.w * bf2f(u11.x));
            r.y = f2bf(cc.x * bf2f(u00.y) + cc.y * bf2f(u01.y) + cc.z * bf2f(u10.y) + cc.w * bf2f(u11.y));
            r.z = f2bf(cc.x * bf2f(u00.z) + cc.y * bf2f(u01.z) + cc.z * bf2f(u10.z) + cc.w * bf2f(u11.z));
            r.w = f2bf(cc.x * bf2f(u00.w) + cc.y * bf2f(u01.w) + cc.z * bf2f(u10.w) + cc.w * bf2f(u11.w));
            *(ushort4*)&Vs[px * 72 + sci0] = r;
        }
        __syncthreads();
        bf16x8 a0 = *(const bf16x8*)&Ws[(m0 + lr) * 72 + lq * 8];
        bf16x8 a1 = *(const bf16x8*)&Ws[(m0 + lr) * 72 + 32 + lq * 8];
#pragma unroll
        for (int t = 0; t < 4; ++t) {
            bf16x8 b0 = *(const bf16x8*)&Vs[(t * 16 + lr) * 72 + lq * 8];
            bf16x8 b1 = *(const bf16x8*)&Vs[(t * 16 + lr) * 72 + 32 + lq * 8];
            acc[t] = __builtin_amdgcn_mfma_f32_16x16x32_bf16(a0, b0, acc[t], 0, 0, 0);
            acc[t] = __builtin_amdgcn_mfma_f32_16x16x32_bf16(a1, b1, acc[t], 0, 0, 0);
        }
    }

#pragma unroll
    for (int t = 0; t < 4; ++t) {
#pragma unroll
        for (int r = 0; r < 4; ++r) {
            int o = m0 + lq * 4 + r;
            out[(size_t)(b * 64 + o) * HWP + rem0 + t * 16 + lr] = acc[t][r];
        }
    }
}

// ---------------------------------------------------------------------------
extern "C" void kernel_launch(void* const* d_in, const int* in_sizes, int n_in,
                              void* d_out, int out_size, void* d_ws, size_t ws_size,
                              hipStream_t stream) {
    const float* x   = (const float*)d_in[0];
    const float* sb  = (const float*)d_in[1];
    const float* gw1 = (const float*)d_in[2];
    const float* gb1 = (const float*)d_in[3];
    const float* gw2 = (const float*)d_in[4];
    const float* gb2 = (const float*)d_in[5];
    const float* lw1 = (const float*)d_in[6];
    const float* lb1 = (const float*)d_in[7];
    const float* lw2 = (const float*)d_in[8];
    const float* lb2 = (const float*)d_in[9];
    const float* fw1 = (const float*)d_in[10];
    const float* fb1 = (const float*)d_in[11];
    const float* fw2 = (const float*)d_in[12];
    const float* fb2 = (const float*)d_in[13];
    const float* mw  = (const float*)d_in[14];
    const float* mb  = (const float*)d_in[15];
    const float* cw  = (const float*)d_in[16];
    const float* cb  = (const float*)d_in[17];
    float* out = (float*)d_out;

    char* w = (char*)d_ws;
    float* gsum = (float*)w;                 w += 1152 * 4;
    unsigned short* cwT  = (unsigned short*)w; w += 36864 * 2;
    unsigned short* Wlm  = (unsigned short*)w; w += 27648 * 2;
    unsigned short* lw2T = (unsigned short*)w; w += 1024 * 2;
    unsigned short* Wf   = (unsigned short*)w; w += 9216 * 2;
    unsigned short* fw2A = (unsigned short*)w; w += 1024 * 2;
    unsigned short* mbuf = (unsigned short*)w; w += (size_t)9 * NPIX * 2;
    float* ysA = (float*)w;                  w += (size_t)9 * NPIX * 4;
    float* xsA = (float*)w;                  w += (size_t)9 * NPIX * 4;
    unsigned short* xT = (unsigned short*)w; w += (size_t)NPIX * 64 * 2;
    unsigned short* lT = (unsigned short*)w;

    k_prep<<<(PREP_N + 255) / 256, 256, 0, stream>>>(cw, lw1, mw, lw2, fw1, fw2,
                                                     cwT, Wlm, lw2T, Wf, fw2A);
    k_glob<<<1, 128, 0, stream>>>(sb, gw1, gb1, gw2, gb2, fw1, gsum);
    k_xT<<<NPIX / 64, 256, 0, stream>>>(x, xT);
    k_locmask<<<NPIX / 128, 256, 0, stream>>>(xT, Wlm, lw2T, lb1, lb2, mb, lT, mbuf);
    k_fuse<<<NPIX / 128, 256, 0, stream>>>(lT, gsum, Wf, fw2A, fb1, fb2, ysA, xsA);
    k_deform<<<NPIX / 64, 256, 0, stream>>>(xT, cwT, cb, ysA, xsA, mbuf, out);
}